// Round 3
// baseline (1460.630 us; speedup 1.0000x reference)
//
#include <hip/hip_runtime.h>
#include <hip/hip_bf16.h>

#define NNODES 4096
#define NBATCH 4096
#define NBLK 8
#define LN_EPS 1e-5f

typedef __attribute__((ext_vector_type(8))) short short8;
typedef __attribute__((ext_vector_type(4))) float f32x4;
typedef __attribute__((ext_vector_type(4))) unsigned short u16x4;
typedef unsigned short u16;

__device__ __forceinline__ u16 bf16_rn(float f) {
  unsigned int u = __builtin_bit_cast(unsigned int, f);
  u += 0x7fffu + ((u >> 16) & 1u);
  return (u16)(u >> 16);
}

__device__ __forceinline__ float bf16_to_f(u16 h) {
  unsigned int u = ((unsigned int)h) << 16;
  return __builtin_bit_cast(float, u);
}

__device__ __forceinline__ void load_lds16(const void* g, void* l) {
  __builtin_amdgcn_global_load_lds((const __attribute__((address_space(1))) void*)g,
                                   (__attribute__((address_space(3))) void*)l,
                                   16, 0, 0);
}

// stage one 256x32 bf16 subtile: 2 x (512 thr x 16B) = 16KB
__device__ __forceinline__ void stage_sub(const u16* g, u16* l) {
  load_lds16(g, l);                                   // rows 0..127
  load_lds16(g + (size_t)128 * NNODES, l + 4096);     // rows 128..255
}

// ---- W f32 -> bf16 convert ----
__global__ __launch_bounds__(256) void convw_kernel(const float* __restrict__ W,
                                                    u16* __restrict__ Wb) {
  int idx = blockIdx.x * 256 + threadIdx.x;
  float4 v = ((const float4*)W)[idx];
  u16x4 o;
  o[0] = bf16_rn(v.x); o[1] = bf16_rn(v.y); o[2] = bf16_rn(v.z); o[3] = bf16_rn(v.w);
  ((u16x4*)Wb)[idx] = o;
}

// ---- row LayerNorm, f32 input (layer 0) -> bf16 out ----
__global__ __launch_bounds__(256) void ln_f32_kernel(const float* __restrict__ x,
                                                     const float* __restrict__ g,
                                                     const float* __restrict__ bt,
                                                     u16* __restrict__ out) {
  int row = blockIdx.x;
  int t = threadIdx.x;
  const float4* xr = (const float4*)(x + (size_t)row * NNODES);
  float4 v[4];
  float s = 0.f, ss = 0.f;
#pragma unroll
  for (int q = 0; q < 4; ++q) {
    v[q] = xr[q * 256 + t];
    s  += v[q].x + v[q].y + v[q].z + v[q].w;
    ss += v[q].x * v[q].x + v[q].y * v[q].y + v[q].z * v[q].z + v[q].w * v[q].w;
  }
#pragma unroll
  for (int off = 32; off >= 1; off >>= 1) {
    s  += __shfl_xor(s, off, 64);
    ss += __shfl_xor(ss, off, 64);
  }
  __shared__ float sh[8];
  int wid = t >> 6, lane = t & 63;
  if (lane == 0) { sh[wid] = s; sh[wid + 4] = ss; }
  __syncthreads();
  s  = sh[0] + sh[1] + sh[2] + sh[3];
  ss = sh[4] + sh[5] + sh[6] + sh[7];
  float mu  = s * (1.f / NNODES);
  float var = ss * (1.f / NNODES) - mu * mu;
  float rs  = rsqrtf(var + LN_EPS);
  u16x4* o = (u16x4*)(out + (size_t)row * NNODES);
  const float4* gv = (const float4*)g;
  const float4* bv = (const float4*)bt;
#pragma unroll
  for (int q = 0; q < 4; ++q) {
    int i = q * 256 + t;
    float4 gg = gv[i], bb = bv[i];
    u16x4 ov;
    ov[0] = bf16_rn((v[q].x - mu) * rs * gg.x + bb.x);
    ov[1] = bf16_rn((v[q].y - mu) * rs * gg.y + bb.y);
    ov[2] = bf16_rn((v[q].z - mu) * rs * gg.z + bb.z);
    ov[3] = bf16_rn((v[q].w - mu) * rs * gg.w + bb.w);
    o[i] = ov;
  }
}

// ---- row LayerNorm, bf16 input (layers 1..7) -> bf16 out ----
__global__ __launch_bounds__(256) void ln_bf16_kernel(const u16* __restrict__ x,
                                                      const float* __restrict__ g,
                                                      const float* __restrict__ bt,
                                                      u16* __restrict__ out) {
  int row = blockIdx.x;
  int t = threadIdx.x;
  const u16* xr = x + (size_t)row * NNODES;
  float f[2][8];
  float s = 0.f, ss = 0.f;
#pragma unroll
  for (int q = 0; q < 2; ++q) {
    short8 v = *(const short8*)(xr + q * 2048 + t * 8);
#pragma unroll
    for (int j = 0; j < 8; ++j) {
      float fv = bf16_to_f((u16)v[j]);
      f[q][j] = fv;
      s += fv; ss += fv * fv;
    }
  }
#pragma unroll
  for (int off = 32; off >= 1; off >>= 1) {
    s  += __shfl_xor(s, off, 64);
    ss += __shfl_xor(ss, off, 64);
  }
  __shared__ float sh[8];
  int wid = t >> 6, lane = t & 63;
  if (lane == 0) { sh[wid] = s; sh[wid + 4] = ss; }
  __syncthreads();
  s  = sh[0] + sh[1] + sh[2] + sh[3];
  ss = sh[4] + sh[5] + sh[6] + sh[7];
  float mu  = s * (1.f / NNODES);
  float var = ss * (1.f / NNODES) - mu * mu;
  float rs  = rsqrtf(var + LN_EPS);
  const float4* gv = (const float4*)g;
  const float4* bv = (const float4*)bt;
#pragma unroll
  for (int q = 0; q < 2; ++q) {
    int base = q * 2048 + t * 8;
    float4 g0 = gv[base / 4], g1 = gv[base / 4 + 1];
    float4 b0 = bv[base / 4], b1 = bv[base / 4 + 1];
    short8 sv;
    sv[0] = (short)bf16_rn((f[q][0] - mu) * rs * g0.x + b0.x);
    sv[1] = (short)bf16_rn((f[q][1] - mu) * rs * g0.y + b0.y);
    sv[2] = (short)bf16_rn((f[q][2] - mu) * rs * g0.z + b0.z);
    sv[3] = (short)bf16_rn((f[q][3] - mu) * rs * g0.w + b0.w);
    sv[4] = (short)bf16_rn((f[q][4] - mu) * rs * g1.x + b1.x);
    sv[5] = (short)bf16_rn((f[q][5] - mu) * rs * g1.y + b1.y);
    sv[6] = (short)bf16_rn((f[q][6] - mu) * rs * g1.z + b1.z);
    sv[7] = (short)bf16_rn((f[q][7] - mu) * rs * g1.w + b1.w);
    *(short8*)(out + (size_t)row * NNODES + base) = sv;
  }
}

// ---- 256x256 bf16 NT GEMM, 8 waves, 4-slot ring, one-phase read-ahead ----
#define GEMM_STEP(S, BC, AC, BN, AN)                                              \
  {                                                                               \
    const int sl_ = (S) & 3;                                                      \
    if ((S) + 3 < NSUB)                                                           \
      stage_sub(Ag + ((S) + 3) * 32, &Alds[((S) + 3) & 3][0] + tid * 8);          \
    __builtin_amdgcn_s_barrier();                                                 \
    asm volatile("s_waitcnt lgkmcnt(0)" ::: "memory");                            \
    __builtin_amdgcn_sched_barrier(0);                                            \
    _Pragma("unroll")                                                             \
    for (int m = 0; m < 4; ++m)                                                   \
      a47[m] = *(const short8*)(&Alds[sl_][0] + aoff + (m + 4) * 512);            \
    __builtin_amdgcn_s_setprio(1);                                                \
    _Pragma("unroll")                                                             \
    for (int m = 0; m < 4; ++m)                                                   \
      _Pragma("unroll")                                                           \
      for (int n = 0; n < 4; ++n)                                                 \
        acc[m][n] = __builtin_amdgcn_mfma_f32_16x16x32_bf16(AC[m], BC[n],         \
                                                            acc[m][n], 0, 0, 0);  \
    __builtin_amdgcn_s_setprio(0);                                                \
    __builtin_amdgcn_s_barrier();                                                 \
    if ((S) + 3 < NSUB)                                                           \
      stage_sub(Bg + ((S) + 3) * 32, &Blds[((S) + 3) & 3][0] + tid * 8);          \
    if ((S) <= NSUB - 4)      asm volatile("s_waitcnt vmcnt(8)" ::: "memory");    \
    else if ((S) == NSUB - 3) asm volatile("s_waitcnt vmcnt(4)" ::: "memory");    \
    else if ((S) == NSUB - 2) asm volatile("s_waitcnt vmcnt(0)" ::: "memory");    \
    __builtin_amdgcn_s_barrier();                                                 \
    asm volatile("s_waitcnt lgkmcnt(0)" ::: "memory");                            \
    __builtin_amdgcn_sched_barrier(0);                                            \
    if ((S) + 1 < NSUB) {                                                         \
      const u16* ab_ = &Alds[((S) + 1) & 3][0] + aoff;                            \
      const u16* bb_ = &Blds[((S) + 1) & 3][0] + boff;                            \
      _Pragma("unroll")                                                           \
      for (int n = 0; n < 4; ++n) BN[n] = *(const short8*)(bb_ + n * 512);        \
      _Pragma("unroll")                                                           \
      for (int m = 0; m < 4; ++m) AN[m] = *(const short8*)(ab_ + m * 512);        \
    }                                                                             \
    __builtin_amdgcn_s_setprio(1);                                                \
    _Pragma("unroll")                                                             \
    for (int m = 0; m < 4; ++m)                                                   \
      _Pragma("unroll")                                                           \
      for (int n = 0; n < 4; ++n)                                                 \
        acc[m + 4][n] = __builtin_amdgcn_mfma_f32_16x16x32_bf16(a47[m], BC[n],    \
                                                                acc[m + 4][n], 0, 0, 0); \
    __builtin_amdgcn_s_setprio(0);                                                \
    __builtin_amdgcn_s_barrier();                                                 \
  }

template <bool OUTF32>
__global__ __launch_bounds__(512, 2) void gemm256_kernel(const u16* __restrict__ A,
                                                         const u16* __restrict__ B,
                                                         const float* __restrict__ bias,
                                                         const float* __restrict__ slope,
                                                         void* __restrict__ Cv) {
  constexpr int Kdim = NNODES;
  constexpr int NSUB = Kdim / 32;
  __shared__ u16 Alds[4][8192];
  __shared__ u16 Blds[4][8192];

  const int tid  = threadIdx.x;
  const int lane = tid & 63;
  const int wid  = tid >> 6;
  const int wr   = wid >> 2;
  const int wc   = wid & 3;

  int bid = blockIdx.x;
  int swz = (bid & 7) * 32 + (bid >> 3);
  const int brow = (swz >> 4) * 256;
  const int bcol = (swz & 15) * 256;

  const int srow = tid >> 2;
  const int scsw = (tid & 3) ^ ((srow >> 1) & 3);
  const u16* Ag = A + (size_t)(brow + srow) * Kdim + scsw * 8;
  const u16* Bg = B + (size_t)(bcol + srow) * Kdim + scsw * 8;

  const int r16 = lane & 15, kq = lane >> 4;
  const int ck  = kq ^ ((r16 >> 1) & 3);
  const int aoff = (wr * 128 + r16) * 32 + ck * 8;
  const int boff = (wc * 64 + r16) * 32 + ck * 8;

  f32x4 acc[8][4] = {};
  short8 bfrA[4], a03A[4], bfrB[4], a03B[4], a47[4];

  // prologue: stage subtiles 0..2; certify 0; read-ahead slot 0 fragments
#pragma unroll
  for (int s = 0; s < 3; ++s) {
    stage_sub(Ag + s * 32, &Alds[s][0] + tid * 8);
    stage_sub(Bg + s * 32, &Blds[s][0] + tid * 8);
  }
  asm volatile("s_waitcnt vmcnt(8)" ::: "memory");
  __builtin_amdgcn_s_barrier();
  {
    const u16* ab = &Alds[0][0] + aoff;
    const u16* bb = &Blds[0][0] + boff;
#pragma unroll
    for (int n = 0; n < 4; ++n) bfrA[n] = *(const short8*)(bb + n * 512);
#pragma unroll
    for (int m = 0; m < 4; ++m) a03A[m] = *(const short8*)(ab + m * 512);
  }

  for (int s = 0; s < NSUB; s += 2) {
    GEMM_STEP(s,     bfrA, a03A, bfrB, a03B)
    GEMM_STEP(s + 1, bfrB, a03B, bfrA, a03A)
  }

  // epilogue: bias + per-feature LeakyReLU
  const int crow0 = brow + wr * 128 + (lane >> 4) * 4;
  const int ccol0 = bcol + wc * 64 + r16;
#pragma unroll
  for (int n = 0; n < 4; ++n) {
    int col = ccol0 + n * 16;
    float bv = bias[col], sv = slope[col];
#pragma unroll
    for (int m = 0; m < 8; ++m) {
      int row0 = crow0 + m * 16;
#pragma unroll
      for (int r = 0; r < 4; ++r) {
        float vv = acc[m][n][r] + bv;
        vv = vv < 0.f ? vv * sv : vv;
        if constexpr (OUTF32) {
          ((float*)Cv)[(size_t)(row0 + r) * NNODES + col] = vv;
        } else {
          ((u16*)Cv)[(size_t)(row0 + r) * NNODES + col] = bf16_rn(vv);
        }
      }
    }
  }
}

extern "C" void kernel_launch(void* const* d_in, const int* in_sizes, int n_in,
                              void* d_out, int out_size, void* d_ws, size_t ws_size,
                              hipStream_t stream) {
  const float* x     = (const float*)d_in[0];
  const float* ln_g  = (const float*)d_in[1];
  const float* ln_b  = (const float*)d_in[2];
  const float* W     = (const float*)d_in[3];
  const float* b     = (const float*)d_in[4];
  const float* slope = (const float*)d_in[5];
  float* out = (float*)d_out;

  char* ws = (char*)d_ws;
  u16* Wbuf  = (u16*)ws;                                   // 32 MB
  u16* lnbuf = (u16*)(ws + (size_t)32 * 1024 * 1024);      // 32 MB
  u16* ybuf  = (u16*)(ws + (size_t)64 * 1024 * 1024);      // 32 MB (bf16 y)

  const size_t WN = (size_t)NNODES * NNODES;

  for (int i = 0; i < NBLK; ++i) {
    convw_kernel<<<dim3(WN / 4 / 256), dim3(256), 0, stream>>>(W + WN * i, Wbuf);
    if (i == 0)
      ln_f32_kernel<<<dim3(NBATCH), dim3(256), 0, stream>>>(x, ln_g, ln_b, lnbuf);
    else
      ln_bf16_kernel<<<dim3(NBATCH), dim3(256), 0, stream>>>(ybuf, ln_g + (size_t)i * NNODES,
                                                             ln_b + (size_t)i * NNODES, lnbuf);
    if (i == NBLK - 1)
      gemm256_kernel<true><<<dim3(256), dim3(512), 0, stream>>>(lnbuf, Wbuf,
                                                                b + (size_t)i * NNODES,
                                                                slope + (size_t)i * NNODES, (void*)out);
    else
      gemm256_kernel<false><<<dim3(256), dim3(512), 0, stream>>>(lnbuf, Wbuf,
                                                                 b + (size_t)i * NNODES,
                                                                 slope + (size_t)i * NNODES, (void*)ybuf);
  }
}

// Round 4
// 1294.403 us; speedup vs baseline: 1.1284x; 1.1284x over previous
//
#include <hip/hip_runtime.h>
#include <hip/hip_bf16.h>

#define NNODES 4096
#define NBATCH 4096
#define NBLK 8
#define LN_EPS 1e-5f

typedef __attribute__((ext_vector_type(8))) short short8;
typedef __attribute__((ext_vector_type(4))) float f32x4;
typedef __attribute__((ext_vector_type(4))) unsigned short u16x4;
typedef unsigned short u16;

__device__ __forceinline__ u16 bf16_rn(float f) {
  unsigned int u = __builtin_bit_cast(unsigned int, f);
  u += 0x7fffu + ((u >> 16) & 1u);
  return (u16)(u >> 16);
}

__device__ __forceinline__ float bf16_to_f(u16 h) {
  unsigned int u = ((unsigned int)h) << 16;
  return __builtin_bit_cast(float, u);
}

__device__ __forceinline__ void load_lds16(const void* g, void* l) {
  __builtin_amdgcn_global_load_lds((const __attribute__((address_space(1))) void*)g,
                                   (__attribute__((address_space(3))) void*)l,
                                   16, 0, 0);
}

// stage one 256x32 bf16 subtile: 2 x (512 thr x 16B) = 16KB
__device__ __forceinline__ void stage_sub(const u16* g, u16* l) {
  load_lds16(g, l);                                   // rows 0..127
  load_lds16(g + (size_t)128 * NNODES, l + 4096);     // rows 128..255
}

// ---- W f32 -> bf16 convert ----
__global__ __launch_bounds__(256) void convw_kernel(const float* __restrict__ W,
                                                    u16* __restrict__ Wb) {
  int idx = blockIdx.x * 256 + threadIdx.x;
  float4 v = ((const float4*)W)[idx];
  u16x4 o;
  o[0] = bf16_rn(v.x); o[1] = bf16_rn(v.y); o[2] = bf16_rn(v.z); o[3] = bf16_rn(v.w);
  ((u16x4*)Wb)[idx] = o;
}

// ---- row LayerNorm, f32 input (layer 0) -> bf16 out ----
__global__ __launch_bounds__(256) void ln_f32_kernel(const float* __restrict__ x,
                                                     const float* __restrict__ g,
                                                     const float* __restrict__ bt,
                                                     u16* __restrict__ out) {
  int row = blockIdx.x;
  int t = threadIdx.x;
  const float4* xr = (const float4*)(x + (size_t)row * NNODES);
  float4 v[4];
  float s = 0.f, ss = 0.f;
#pragma unroll
  for (int q = 0; q < 4; ++q) {
    v[q] = xr[q * 256 + t];
    s  += v[q].x + v[q].y + v[q].z + v[q].w;
    ss += v[q].x * v[q].x + v[q].y * v[q].y + v[q].z * v[q].z + v[q].w * v[q].w;
  }
#pragma unroll
  for (int off = 32; off >= 1; off >>= 1) {
    s  += __shfl_xor(s, off, 64);
    ss += __shfl_xor(ss, off, 64);
  }
  __shared__ float sh[8];
  int wid = t >> 6, lane = t & 63;
  if (lane == 0) { sh[wid] = s; sh[wid + 4] = ss; }
  __syncthreads();
  s  = sh[0] + sh[1] + sh[2] + sh[3];
  ss = sh[4] + sh[5] + sh[6] + sh[7];
  float mu  = s * (1.f / NNODES);
  float var = ss * (1.f / NNODES) - mu * mu;
  float rs  = rsqrtf(var + LN_EPS);
  u16x4* o = (u16x4*)(out + (size_t)row * NNODES);
  const float4* gv = (const float4*)g;
  const float4* bv = (const float4*)bt;
#pragma unroll
  for (int q = 0; q < 4; ++q) {
    int i = q * 256 + t;
    float4 gg = gv[i], bb = bv[i];
    u16x4 ov;
    ov[0] = bf16_rn((v[q].x - mu) * rs * gg.x + bb.x);
    ov[1] = bf16_rn((v[q].y - mu) * rs * gg.y + bb.y);
    ov[2] = bf16_rn((v[q].z - mu) * rs * gg.z + bb.z);
    ov[3] = bf16_rn((v[q].w - mu) * rs * gg.w + bb.w);
    o[i] = ov;
  }
}

// ---- row LayerNorm, bf16 input (layers 1..7) -> bf16 out ----
__global__ __launch_bounds__(256) void ln_bf16_kernel(const u16* __restrict__ x,
                                                      const float* __restrict__ g,
                                                      const float* __restrict__ bt,
                                                      u16* __restrict__ out) {
  int row = blockIdx.x;
  int t = threadIdx.x;
  const u16* xr = x + (size_t)row * NNODES;
  float f[2][8];
  float s = 0.f, ss = 0.f;
#pragma unroll
  for (int q = 0; q < 2; ++q) {
    short8 v = *(const short8*)(xr + q * 2048 + t * 8);
#pragma unroll
    for (int j = 0; j < 8; ++j) {
      float fv = bf16_to_f((u16)v[j]);
      f[q][j] = fv;
      s += fv; ss += fv * fv;
    }
  }
#pragma unroll
  for (int off = 32; off >= 1; off >>= 1) {
    s  += __shfl_xor(s, off, 64);
    ss += __shfl_xor(ss, off, 64);
  }
  __shared__ float sh[8];
  int wid = t >> 6, lane = t & 63;
  if (lane == 0) { sh[wid] = s; sh[wid + 4] = ss; }
  __syncthreads();
  s  = sh[0] + sh[1] + sh[2] + sh[3];
  ss = sh[4] + sh[5] + sh[6] + sh[7];
  float mu  = s * (1.f / NNODES);
  float var = ss * (1.f / NNODES) - mu * mu;
  float rs  = rsqrtf(var + LN_EPS);
  const float4* gv = (const float4*)g;
  const float4* bv = (const float4*)bt;
#pragma unroll
  for (int q = 0; q < 2; ++q) {
    int base = q * 2048 + t * 8;
    float4 g0 = gv[base / 4], g1 = gv[base / 4 + 1];
    float4 b0 = bv[base / 4], b1 = bv[base / 4 + 1];
    short8 sv;
    sv[0] = (short)bf16_rn((f[q][0] - mu) * rs * g0.x + b0.x);
    sv[1] = (short)bf16_rn((f[q][1] - mu) * rs * g0.y + b0.y);
    sv[2] = (short)bf16_rn((f[q][2] - mu) * rs * g0.z + b0.z);
    sv[3] = (short)bf16_rn((f[q][3] - mu) * rs * g0.w + b0.w);
    sv[4] = (short)bf16_rn((f[q][4] - mu) * rs * g1.x + b1.x);
    sv[5] = (short)bf16_rn((f[q][5] - mu) * rs * g1.y + b1.y);
    sv[6] = (short)bf16_rn((f[q][6] - mu) * rs * g1.z + b1.z);
    sv[7] = (short)bf16_rn((f[q][7] - mu) * rs * g1.w + b1.w);
    *(short8*)(out + (size_t)row * NNODES + base) = sv;
  }
}

// ---- 256x256 bf16 NT GEMM, 8 waves, 4-slot LDS ring (round-2 schedule) ----
template <bool OUTF32>
__global__ __launch_bounds__(512, 2) void gemm256_kernel(const u16* __restrict__ A,
                                                         const u16* __restrict__ B,
                                                         const float* __restrict__ bias,
                                                         const float* __restrict__ slope,
                                                         void* __restrict__ Cv) {
  constexpr int Kdim = NNODES;
  constexpr int NSUB = Kdim / 32;   // 128 subtiles of K=32
  __shared__ u16 Alds[4][8192];     // 4 ring slots x 256x32 bf16 = 64KB
  __shared__ u16 Blds[4][8192];     // 64KB

  const int tid  = threadIdx.x;
  const int lane = tid & 63;
  const int wid  = tid >> 6;
  const int wr   = wid >> 2;        // 0..1 : row half (128 rows)
  const int wc   = wid & 3;         // 0..3 : col quarter (64 cols)

  // XCD-aware bijective swizzle (256 blocks, 8 XCDs)
  int bid = blockIdx.x;
  int swz = (bid & 7) * 32 + (bid >> 3);
  const int brow = (swz >> 4) * 256;
  const int bcol = (swz & 15) * 256;

  // staging: thread t -> row t/4 (+128 for 2nd instr), 16B chunk t&3, XOR-swizzled source
  const int srow = tid >> 2;
  const int scsw = (tid & 3) ^ ((srow >> 1) & 3);
  const u16* Ag = A + (size_t)(brow + srow) * Kdim + scsw * 8;
  const u16* Bg = B + (size_t)(bcol + srow) * Kdim + scsw * 8;

  // ds_read: lane -> row r16, k-chunk kq, swizzled chunk ck
  const int r16 = lane & 15, kq = lane >> 4;
  const int ck  = kq ^ ((r16 >> 1) & 3);
  const int aoff = (wr * 128 + r16) * 32 + ck * 8;  // + m*512 per frag
  const int boff = (wc * 64 + r16) * 32 + ck * 8;   // + n*512 per frag

  f32x4 acc[8][4] = {};

  // prologue: stage subtiles 0,1,2 (12 loads); certify subtile 0 cross-wave
#pragma unroll
  for (int s = 0; s < 3; ++s) {
    stage_sub(Ag + s * 32, &Alds[s][0] + tid * 8);
    stage_sub(Bg + s * 32, &Blds[s][0] + tid * 8);
  }
  asm volatile("s_waitcnt vmcnt(8)" ::: "memory");
  __builtin_amdgcn_s_barrier();

  for (int s = 0; s < NSUB; ++s) {
    const int sl = s & 3;
    const u16* abase = &Alds[sl][0] + aoff;
    const u16* bbase = &Blds[sl][0] + boff;
    short8 afr[4], bfr[4];

    // ---------- phase 0: B all + A m0-3, stage A(s+3) ----------
#pragma unroll
    for (int n = 0; n < 4; ++n) bfr[n] = *(const short8*)(bbase + n * 512);
#pragma unroll
    for (int m = 0; m < 4; ++m) afr[m] = *(const short8*)(abase + m * 512);
    if (s + 3 < NSUB) stage_sub(Ag + (s + 3) * 32, &Alds[(s + 3) & 3][0] + tid * 8);
    __builtin_amdgcn_s_barrier();
    asm volatile("s_waitcnt lgkmcnt(0)" ::: "memory");
    __builtin_amdgcn_sched_barrier(0);
    __builtin_amdgcn_s_setprio(1);
#pragma unroll
    for (int m = 0; m < 4; ++m)
#pragma unroll
      for (int n = 0; n < 4; ++n)
        acc[m][n] = __builtin_amdgcn_mfma_f32_16x16x32_bf16(afr[m], bfr[n], acc[m][n], 0, 0, 0);
    __builtin_amdgcn_s_setprio(0);
    __builtin_amdgcn_s_barrier();

    // ---------- phase 1: A m4-7, stage B(s+3), certify subtile s+1 ----------
#pragma unroll
    for (int m = 0; m < 4; ++m) afr[m] = *(const short8*)(abase + (m + 4) * 512);
    if (s + 3 < NSUB) stage_sub(Bg + (s + 3) * 32, &Blds[(s + 3) & 3][0] + tid * 8);
    // counted vmcnt BEFORE the barrier => cross-wave guarantee for slot (s+1)&3
    if (s <= NSUB - 4)      asm volatile("s_waitcnt vmcnt(8)" ::: "memory");
    else if (s == NSUB - 3) asm volatile("s_waitcnt vmcnt(4)" ::: "memory");
    else if (s == NSUB - 2) asm volatile("s_waitcnt vmcnt(0)" ::: "memory");
    __builtin_amdgcn_s_barrier();
    asm volatile("s_waitcnt lgkmcnt(0)" ::: "memory");
    __builtin_amdgcn_sched_barrier(0);
    __builtin_amdgcn_s_setprio(1);
#pragma unroll
    for (int m = 0; m < 4; ++m)
#pragma unroll
      for (int n = 0; n < 4; ++n)
        acc[m + 4][n] = __builtin_amdgcn_mfma_f32_16x16x32_bf16(afr[m], bfr[n], acc[m + 4][n], 0, 0, 0);
    __builtin_amdgcn_s_setprio(0);
    __builtin_amdgcn_s_barrier();
  }

  // epilogue: bias + per-feature LeakyReLU
  const int crow0 = brow + wr * 128 + (lane >> 4) * 4;
  const int ccol0 = bcol + wc * 64 + r16;
#pragma unroll
  for (int n = 0; n < 4; ++n) {
    int col = ccol0 + n * 16;
    float bv = bias[col], sv = slope[col];
#pragma unroll
    for (int m = 0; m < 8; ++m) {
      int row0 = crow0 + m * 16;
#pragma unroll
      for (int r = 0; r < 4; ++r) {
        float vv = acc[m][n][r] + bv;
        vv = vv < 0.f ? vv * sv : vv;
        if constexpr (OUTF32) {
          ((float*)Cv)[(size_t)(row0 + r) * NNODES + col] = vv;
        } else {
          ((u16*)Cv)[(size_t)(row0 + r) * NNODES + col] = bf16_rn(vv);
        }
      }
    }
  }
}

extern "C" void kernel_launch(void* const* d_in, const int* in_sizes, int n_in,
                              void* d_out, int out_size, void* d_ws, size_t ws_size,
                              hipStream_t stream) {
  const float* x     = (const float*)d_in[0];
  const float* ln_g  = (const float*)d_in[1];
  const float* ln_b  = (const float*)d_in[2];
  const float* W     = (const float*)d_in[3];
  const float* b     = (const float*)d_in[4];
  const float* slope = (const float*)d_in[5];
  float* out = (float*)d_out;

  char* ws = (char*)d_ws;
  u16* Wbuf  = (u16*)ws;                                   // 32 MB
  u16* lnbuf = (u16*)(ws + (size_t)32 * 1024 * 1024);      // 32 MB
  u16* ybuf  = (u16*)(ws + (size_t)64 * 1024 * 1024);      // 32 MB (bf16 y)

  const size_t WN = (size_t)NNODES * NNODES;

  for (int i = 0; i < NBLK; ++i) {
    convw_kernel<<<dim3(WN / 4 / 256), dim3(256), 0, stream>>>(W + WN * i, Wbuf);
    if (i == 0)
      ln_f32_kernel<<<dim3(NBATCH), dim3(256), 0, stream>>>(x, ln_g, ln_b, lnbuf);
    else
      ln_bf16_kernel<<<dim3(NBATCH), dim3(256), 0, stream>>>(ybuf, ln_g + (size_t)i * NNODES,
                                                             ln_b + (size_t)i * NNODES, lnbuf);
    if (i == NBLK - 1)
      gemm256_kernel<true><<<dim3(256), dim3(512), 0, stream>>>(lnbuf, Wbuf,
                                                                b + (size_t)i * NNODES,
                                                                slope + (size_t)i * NNODES, (void*)out);
    else
      gemm256_kernel<false><<<dim3(256), dim3(512), 0, stream>>>(lnbuf, Wbuf,
                                                                 b + (size_t)i * NNODES,
                                                                 slope + (size_t)i * NNODES, (void*)ybuf);
  }
}

// Round 5
// 1228.808 us; speedup vs baseline: 1.1887x; 1.0534x over previous
//
#include <hip/hip_runtime.h>
#include <hip/hip_bf16.h>

#define NNODES 4096
#define NBATCH 4096
#define NBLK 8
#define LN_EPS 1e-5f

typedef __attribute__((ext_vector_type(8))) short short8;
typedef __attribute__((ext_vector_type(4))) float f32x4;
typedef __attribute__((ext_vector_type(4))) unsigned short u16x4;
typedef unsigned short u16;

__device__ __forceinline__ u16 bf16_rn(float f) {
  unsigned int u = __builtin_bit_cast(unsigned int, f);
  u += 0x7fffu + ((u >> 16) & 1u);
  return (u16)(u >> 16);
}

__device__ __forceinline__ float bf16_to_f(u16 h) {
  unsigned int u = ((unsigned int)h) << 16;
  return __builtin_bit_cast(float, u);
}

__device__ __forceinline__ void load_lds16(const void* g, void* l) {
  __builtin_amdgcn_global_load_lds((const __attribute__((address_space(1))) void*)g,
                                   (__attribute__((address_space(3))) void*)l,
                                   16, 0, 0);
}

// stage one 256x32 bf16 subtile: 2 x (512 thr x 16B) = 16KB
__device__ __forceinline__ void stage_sub(const u16* g, u16* l) {
  load_lds16(g, l);                                   // rows 0..127
  load_lds16(g + (size_t)128 * NNODES, l + 4096);     // rows 128..255
}

// ---- W f32 -> bf16 convert ----
__global__ __launch_bounds__(256) void convw_kernel(const float* __restrict__ W,
                                                    u16* __restrict__ Wb) {
  int idx = blockIdx.x * 256 + threadIdx.x;
  float4 v = ((const float4*)W)[idx];
  u16x4 o;
  o[0] = bf16_rn(v.x); o[1] = bf16_rn(v.y); o[2] = bf16_rn(v.z); o[3] = bf16_rn(v.w);
  ((u16x4*)Wb)[idx] = o;
}

// ---- row LayerNorm, f32 input (layer 0) -> bf16 out ----
__global__ __launch_bounds__(256) void ln_f32_kernel(const float* __restrict__ x,
                                                     const float* __restrict__ g,
                                                     const float* __restrict__ bt,
                                                     u16* __restrict__ out) {
  int row = blockIdx.x;
  int t = threadIdx.x;
  const float4* xr = (const float4*)(x + (size_t)row * NNODES);
  float4 v[4];
  float s = 0.f, ss = 0.f;
#pragma unroll
  for (int q = 0; q < 4; ++q) {
    v[q] = xr[q * 256 + t];
    s  += v[q].x + v[q].y + v[q].z + v[q].w;
    ss += v[q].x * v[q].x + v[q].y * v[q].y + v[q].z * v[q].z + v[q].w * v[q].w;
  }
#pragma unroll
  for (int off = 32; off >= 1; off >>= 1) {
    s  += __shfl_xor(s, off, 64);
    ss += __shfl_xor(ss, off, 64);
  }
  __shared__ float sh[8];
  int wid = t >> 6, lane = t & 63;
  if (lane == 0) { sh[wid] = s; sh[wid + 4] = ss; }
  __syncthreads();
  s  = sh[0] + sh[1] + sh[2] + sh[3];
  ss = sh[4] + sh[5] + sh[6] + sh[7];
  float mu  = s * (1.f / NNODES);
  float var = ss * (1.f / NNODES) - mu * mu;
  float rs  = rsqrtf(var + LN_EPS);
  u16x4* o = (u16x4*)(out + (size_t)row * NNODES);
  const float4* gv = (const float4*)g;
  const float4* bv = (const float4*)bt;
#pragma unroll
  for (int q = 0; q < 4; ++q) {
    int i = q * 256 + t;
    float4 gg = gv[i], bb = bv[i];
    u16x4 ov;
    ov[0] = bf16_rn((v[q].x - mu) * rs * gg.x + bb.x);
    ov[1] = bf16_rn((v[q].y - mu) * rs * gg.y + bb.y);
    ov[2] = bf16_rn((v[q].z - mu) * rs * gg.z + bb.z);
    ov[3] = bf16_rn((v[q].w - mu) * rs * gg.w + bb.w);
    o[i] = ov;
  }
}

// ---- row LayerNorm, bf16 input (layers 1..7) -> bf16 out ----
__global__ __launch_bounds__(256) void ln_bf16_kernel(const u16* __restrict__ x,
                                                      const float* __restrict__ g,
                                                      const float* __restrict__ bt,
                                                      u16* __restrict__ out) {
  int row = blockIdx.x;
  int t = threadIdx.x;
  const u16* xr = x + (size_t)row * NNODES;
  float f[2][8];
  float s = 0.f, ss = 0.f;
#pragma unroll
  for (int q = 0; q < 2; ++q) {
    short8 v = *(const short8*)(xr + q * 2048 + t * 8);
#pragma unroll
    for (int j = 0; j < 8; ++j) {
      float fv = bf16_to_f((u16)v[j]);
      f[q][j] = fv;
      s += fv; ss += fv * fv;
    }
  }
#pragma unroll
  for (int off = 32; off >= 1; off >>= 1) {
    s  += __shfl_xor(s, off, 64);
    ss += __shfl_xor(ss, off, 64);
  }
  __shared__ float sh[8];
  int wid = t >> 6, lane = t & 63;
  if (lane == 0) { sh[wid] = s; sh[wid + 4] = ss; }
  __syncthreads();
  s  = sh[0] + sh[1] + sh[2] + sh[3];
  ss = sh[4] + sh[5] + sh[6] + sh[7];
  float mu  = s * (1.f / NNODES);
  float var = ss * (1.f / NNODES) - mu * mu;
  float rs  = rsqrtf(var + LN_EPS);
  const float4* gv = (const float4*)g;
  const float4* bv = (const float4*)bt;
#pragma unroll
  for (int q = 0; q < 2; ++q) {
    int base = q * 2048 + t * 8;
    float4 g0 = gv[base / 4], g1 = gv[base / 4 + 1];
    float4 b0 = bv[base / 4], b1 = bv[base / 4 + 1];
    short8 sv;
    sv[0] = (short)bf16_rn((f[q][0] - mu) * rs * g0.x + b0.x);
    sv[1] = (short)bf16_rn((f[q][1] - mu) * rs * g0.y + b0.y);
    sv[2] = (short)bf16_rn((f[q][2] - mu) * rs * g0.z + b0.z);
    sv[3] = (short)bf16_rn((f[q][3] - mu) * rs * g0.w + b0.w);
    sv[4] = (short)bf16_rn((f[q][4] - mu) * rs * g1.x + b1.x);
    sv[5] = (short)bf16_rn((f[q][5] - mu) * rs * g1.y + b1.y);
    sv[6] = (short)bf16_rn((f[q][6] - mu) * rs * g1.z + b1.z);
    sv[7] = (short)bf16_rn((f[q][7] - mu) * rs * g1.w + b1.w);
    *(short8*)(out + (size_t)row * NNODES + base) = sv;
  }
}

// ---- 256x256 bf16 NT GEMM, 8 waves, 4-slot LDS ring, ONE barrier/subtile ----
// Race-freedom: max wave skew = 1 subtile (bounded by the barrier); every
// slot overwrite (stage into (s+3)&3 = (s-1)&3) happens after the barrier
// that followed all waves' lgkmcnt(0)-drained reads of that slot; per-wave
// vmcnt(8) before the barrier certifies slot s+1 (outstanding after it =
// 8 most-recent loads = slots s+2,s+3 only).
template <bool OUTF32>
__global__ __launch_bounds__(512, 2) void gemm256_kernel(const u16* __restrict__ A,
                                                         const u16* __restrict__ B,
                                                         const float* __restrict__ bias,
                                                         const float* __restrict__ slope,
                                                         void* __restrict__ Cv) {
  constexpr int Kdim = NNODES;
  constexpr int NSUB = Kdim / 32;   // 128 subtiles of K=32
  __shared__ u16 Alds[4][8192];     // 4 ring slots x 256x32 bf16 = 64KB
  __shared__ u16 Blds[4][8192];     // 64KB

  const int tid  = threadIdx.x;
  const int lane = tid & 63;
  const int wid  = tid >> 6;
  const int wr   = wid >> 2;        // 0..1 : row half (128 rows)
  const int wc   = wid & 3;         // 0..3 : col quarter (64 cols)

  // XCD-aware bijective swizzle (256 blocks, 8 XCDs)
  int bid = blockIdx.x;
  int swz = (bid & 7) * 32 + (bid >> 3);
  const int brow = (swz >> 4) * 256;
  const int bcol = (swz & 15) * 256;

  // staging: thread t -> row t/4 (+128 for 2nd instr), 16B chunk t&3, XOR-swizzled source
  const int srow = tid >> 2;
  const int scsw = (tid & 3) ^ ((srow >> 1) & 3);
  const u16* Ag = A + (size_t)(brow + srow) * Kdim + scsw * 8;
  const u16* Bg = B + (size_t)(bcol + srow) * Kdim + scsw * 8;

  // ds_read: lane -> row r16, k-chunk kq, swizzled chunk ck
  const int r16 = lane & 15, kq = lane >> 4;
  const int ck  = kq ^ ((r16 >> 1) & 3);
  const int aoff = (wr * 128 + r16) * 32 + ck * 8;  // + m*512 per frag
  const int boff = (wc * 64 + r16) * 32 + ck * 8;   // + n*512 per frag

  f32x4 acc[8][4] = {};

  // prologue: stage subtiles 0,1,2 (12 loads); certify subtile 0 cross-wave
#pragma unroll
  for (int s = 0; s < 3; ++s) {
    stage_sub(Ag + s * 32, &Alds[s][0] + tid * 8);
    stage_sub(Bg + s * 32, &Blds[s][0] + tid * 8);
  }
  asm volatile("s_waitcnt vmcnt(8)" ::: "memory");
  __builtin_amdgcn_s_barrier();

  for (int s = 0; s < NSUB; ++s) {
    const int sl = s & 3;
    const u16* abase = &Alds[sl][0] + aoff;
    const u16* bbase = &Blds[sl][0] + boff;
    short8 afr[4], bfr[4];

    // ---------- phase 0: read B all + A m0-3, stage A(s+3), MFMA upper ----------
#pragma unroll
    for (int n = 0; n < 4; ++n) bfr[n] = *(const short8*)(bbase + n * 512);
#pragma unroll
    for (int m = 0; m < 4; ++m) afr[m] = *(const short8*)(abase + m * 512);
    if (s + 3 < NSUB) stage_sub(Ag + (s + 3) * 32, &Alds[(s + 3) & 3][0] + tid * 8);
    asm volatile("s_waitcnt lgkmcnt(0)" ::: "memory");
    __builtin_amdgcn_sched_barrier(0);
    __builtin_amdgcn_s_setprio(1);
#pragma unroll
    for (int m = 0; m < 4; ++m)
#pragma unroll
      for (int n = 0; n < 4; ++n)
        acc[m][n] = __builtin_amdgcn_mfma_f32_16x16x32_bf16(afr[m], bfr[n], acc[m][n], 0, 0, 0);
    __builtin_amdgcn_s_setprio(0);

    // ---------- phase 1: read A m4-7, stage B(s+3), certify s+1, MFMA lower ----------
#pragma unroll
    for (int m = 0; m < 4; ++m) afr[m] = *(const short8*)(abase + (m + 4) * 512);
    if (s + 3 < NSUB) stage_sub(Bg + (s + 3) * 32, &Blds[(s + 3) & 3][0] + tid * 8);
    if (s <= NSUB - 4)      asm volatile("s_waitcnt vmcnt(8)" ::: "memory");
    else if (s == NSUB - 3) asm volatile("s_waitcnt vmcnt(4)" ::: "memory");
    else if (s == NSUB - 2) asm volatile("s_waitcnt vmcnt(0)" ::: "memory");
    asm volatile("s_waitcnt lgkmcnt(0)" ::: "memory");
    __builtin_amdgcn_sched_barrier(0);
    __builtin_amdgcn_s_setprio(1);
#pragma unroll
    for (int m = 0; m < 4; ++m)
#pragma unroll
      for (int n = 0; n < 4; ++n)
        acc[m + 4][n] = __builtin_amdgcn_mfma_f32_16x16x32_bf16(afr[m], bfr[n], acc[m + 4][n], 0, 0, 0);
    __builtin_amdgcn_s_setprio(0);
    __builtin_amdgcn_s_barrier();   // single barrier per subtile
  }

  // epilogue: bias + per-feature LeakyReLU
  const int crow0 = brow + wr * 128 + (lane >> 4) * 4;
  const int ccol0 = bcol + wc * 64 + r16;
#pragma unroll
  for (int n = 0; n < 4; ++n) {
    int col = ccol0 + n * 16;
    float bv = bias[col], sv = slope[col];
#pragma unroll
    for (int m = 0; m < 8; ++m) {
      int row0 = crow0 + m * 16;
#pragma unroll
      for (int r = 0; r < 4; ++r) {
        float vv = acc[m][n][r] + bv;
        vv = vv < 0.f ? vv * sv : vv;
        if constexpr (OUTF32) {
          ((float*)Cv)[(size_t)(row0 + r) * NNODES + col] = vv;
        } else {
          ((u16*)Cv)[(size_t)(row0 + r) * NNODES + col] = bf16_rn(vv);
        }
      }
    }
  }
}

extern "C" void kernel_launch(void* const* d_in, const int* in_sizes, int n_in,
                              void* d_out, int out_size, void* d_ws, size_t ws_size,
                              hipStream_t stream) {
  const float* x     = (const float*)d_in[0];
  const float* ln_g  = (const float*)d_in[1];
  const float* ln_b  = (const float*)d_in[2];
  const float* W     = (const float*)d_in[3];
  const float* b     = (const float*)d_in[4];
  const float* slope = (const float*)d_in[5];
  float* out = (float*)d_out;

  char* ws = (char*)d_ws;
  u16* Wbuf  = (u16*)ws;                                   // 32 MB
  u16* lnbuf = (u16*)(ws + (size_t)32 * 1024 * 1024);      // 32 MB
  u16* ybuf  = (u16*)(ws + (size_t)64 * 1024 * 1024);      // 32 MB (bf16 y)

  const size_t WN = (size_t)NNODES * NNODES;

  for (int i = 0; i < NBLK; ++i) {
    convw_kernel<<<dim3(WN / 4 / 256), dim3(256), 0, stream>>>(W + WN * i, Wbuf);
    if (i == 0)
      ln_f32_kernel<<<dim3(NBATCH), dim3(256), 0, stream>>>(x, ln_g, ln_b, lnbuf);
    else
      ln_bf16_kernel<<<dim3(NBATCH), dim3(256), 0, stream>>>(ybuf, ln_g + (size_t)i * NNODES,
                                                             ln_b + (size_t)i * NNODES, lnbuf);
    if (i == NBLK - 1)
      gemm256_kernel<true><<<dim3(256), dim3(512), 0, stream>>>(lnbuf, Wbuf,
                                                                b + (size_t)i * NNODES,
                                                                slope + (size_t)i * NNODES, (void*)out);
    else
      gemm256_kernel<false><<<dim3(256), dim3(512), 0, stream>>>(lnbuf, Wbuf,
                                                                 b + (size_t)i * NNODES,
                                                                 slope + (size_t)i * NNODES, (void*)ybuf);
  }
}

// Round 6
// 1182.131 us; speedup vs baseline: 1.2356x; 1.0395x over previous
//
#include <hip/hip_runtime.h>
#include <hip/hip_bf16.h>

#define NNODES 4096
#define NBATCH 4096
#define NBLK 8
#define LN_EPS 1e-5f

typedef __attribute__((ext_vector_type(8))) short short8;
typedef __attribute__((ext_vector_type(4))) float f32x4;
typedef __attribute__((ext_vector_type(4))) unsigned short u16x4;
typedef unsigned short u16;

__device__ __forceinline__ u16 bf16_rn(float f) {
  unsigned int u = __builtin_bit_cast(unsigned int, f);
  u += 0x7fffu + ((u >> 16) & 1u);
  return (u16)(u >> 16);
}

__device__ __forceinline__ float bf16_to_f(u16 h) {
  unsigned int u = ((unsigned int)h) << 16;
  return __builtin_bit_cast(float, u);
}

__device__ __forceinline__ void load_lds16(const void* g, void* l) {
  __builtin_amdgcn_global_load_lds((const __attribute__((address_space(1))) void*)g,
                                   (__attribute__((address_space(3))) void*)l,
                                   16, 0, 0);
}

// stage one 256x32 bf16 subtile: 2 x (512 thr x 16B) = 16KB
__device__ __forceinline__ void stage_sub(const u16* g, u16* l) {
  load_lds16(g, l);                                   // rows 0..127
  load_lds16(g + (size_t)128 * NNODES, l + 4096);     // rows 128..255
}

// ---- merged prep: blocks [0,16384) convert W f32->bf16; [16384,16384+4096) LayerNorm ----
template <bool LNF32>
__global__ __launch_bounds__(256) void prep_kernel(const float* __restrict__ W,
                                                   u16* __restrict__ Wb,
                                                   const void* __restrict__ xin,
                                                   const float* __restrict__ g,
                                                   const float* __restrict__ bt,
                                                   u16* __restrict__ lnout) {
  __shared__ float sh[8];
  int t = threadIdx.x;
  if (blockIdx.x < 16384) {
    int idx = blockIdx.x * 256 + t;
    float4 v = ((const float4*)W)[idx];
    u16x4 o;
    o[0] = bf16_rn(v.x); o[1] = bf16_rn(v.y); o[2] = bf16_rn(v.z); o[3] = bf16_rn(v.w);
    ((u16x4*)Wb)[idx] = o;
    return;
  }
  int row = blockIdx.x - 16384;
  float f[16];
  float s = 0.f, ss = 0.f;
  if constexpr (LNF32) {
    const float4* xr = (const float4*)((const float*)xin + (size_t)row * NNODES);
#pragma unroll
    for (int q = 0; q < 4; ++q) {
      float4 v = xr[q * 256 + t];
      f[q * 4 + 0] = v.x; f[q * 4 + 1] = v.y; f[q * 4 + 2] = v.z; f[q * 4 + 3] = v.w;
      s  += v.x + v.y + v.z + v.w;
      ss += v.x * v.x + v.y * v.y + v.z * v.z + v.w * v.w;
    }
  } else {
    const u16* xr = (const u16*)xin + (size_t)row * NNODES;
#pragma unroll
    for (int q = 0; q < 2; ++q) {
      short8 v = *(const short8*)(xr + q * 2048 + t * 8);
#pragma unroll
      for (int j = 0; j < 8; ++j) {
        float fv = bf16_to_f((u16)v[j]);
        f[q * 8 + j] = fv;
        s += fv; ss += fv * fv;
      }
    }
  }
#pragma unroll
  for (int off = 32; off >= 1; off >>= 1) {
    s  += __shfl_xor(s, off, 64);
    ss += __shfl_xor(ss, off, 64);
  }
  int wid = t >> 6, lane = t & 63;
  if (lane == 0) { sh[wid] = s; sh[wid + 4] = ss; }
  __syncthreads();
  s  = sh[0] + sh[1] + sh[2] + sh[3];
  ss = sh[4] + sh[5] + sh[6] + sh[7];
  float mu  = s * (1.f / NNODES);
  float var = ss * (1.f / NNODES) - mu * mu;
  float rs  = rsqrtf(var + LN_EPS);
  const float* gp = g;
  const float* bp = bt;
  if constexpr (LNF32) {
    // layout: f[q*4+j] at element q*1024 + t*4 + j
    u16x4* o = (u16x4*)(lnout + (size_t)row * NNODES);
    const float4* gv = (const float4*)gp;
    const float4* bv = (const float4*)bp;
#pragma unroll
    for (int q = 0; q < 4; ++q) {
      int i = q * 256 + t;
      float4 gg = gv[i], bb = bv[i];
      u16x4 ov;
      ov[0] = bf16_rn((f[q * 4 + 0] - mu) * rs * gg.x + bb.x);
      ov[1] = bf16_rn((f[q * 4 + 1] - mu) * rs * gg.y + bb.y);
      ov[2] = bf16_rn((f[q * 4 + 2] - mu) * rs * gg.z + bb.z);
      ov[3] = bf16_rn((f[q * 4 + 3] - mu) * rs * gg.w + bb.w);
      o[i] = ov;
    }
  } else {
#pragma unroll
    for (int q = 0; q < 2; ++q) {
      int base = q * 2048 + t * 8;
      float4 g0 = ((const float4*)gp)[base / 4], g1 = ((const float4*)gp)[base / 4 + 1];
      float4 b0 = ((const float4*)bp)[base / 4], b1 = ((const float4*)bp)[base / 4 + 1];
      short8 sv;
      sv[0] = (short)bf16_rn((f[q * 8 + 0] - mu) * rs * g0.x + b0.x);
      sv[1] = (short)bf16_rn((f[q * 8 + 1] - mu) * rs * g0.y + b0.y);
      sv[2] = (short)bf16_rn((f[q * 8 + 2] - mu) * rs * g0.z + b0.z);
      sv[3] = (short)bf16_rn((f[q * 8 + 3] - mu) * rs * g0.w + b0.w);
      sv[4] = (short)bf16_rn((f[q * 8 + 4] - mu) * rs * g1.x + b1.x);
      sv[5] = (short)bf16_rn((f[q * 8 + 5] - mu) * rs * g1.y + b1.y);
      sv[6] = (short)bf16_rn((f[q * 8 + 6] - mu) * rs * g1.z + b1.z);
      sv[7] = (short)bf16_rn((f[q * 8 + 7] - mu) * rs * g1.w + b1.w);
      *(short8*)(lnout + (size_t)row * NNODES + base) = sv;
    }
  }
}

// ---- 256x256 bf16 NT GEMM, 8 waves, 4-slot LDS ring, one barrier/subtile,
//      all-12 ds_read upfront + partial lgkm waits (a47 drains under upper MFMA) ----
// Race-freedom: max wave skew = 1 subtile (single barrier); slot overwrite
// (stage into (s+3)&3 = (s-1)&3) happens after the barrier that followed all
// waves' lgkmcnt-drained reads of that slot; per-wave vmcnt(8) AFTER both
// stage issues leaves exactly slots s+2,s+3 outstanding => slot s+1 certified
// cross-wave at the barrier.
template <bool OUTF32>
__global__ __launch_bounds__(512, 2) void gemm256_kernel(const u16* __restrict__ A,
                                                         const u16* __restrict__ B,
                                                         const float* __restrict__ bias,
                                                         const float* __restrict__ slope,
                                                         void* __restrict__ Cv) {
  constexpr int Kdim = NNODES;
  constexpr int NSUB = Kdim / 32;   // 128 subtiles of K=32
  __shared__ u16 Alds[4][8192];     // 4 ring slots x 256x32 bf16 = 64KB
  __shared__ u16 Blds[4][8192];     // 64KB

  const int tid  = threadIdx.x;
  const int lane = tid & 63;
  const int wid  = tid >> 6;
  const int wr   = wid >> 2;        // 0..1 : row half (128 rows)
  const int wc   = wid & 3;         // 0..3 : col quarter (64 cols)

  // XCD-aware bijective swizzle (256 blocks, 8 XCDs)
  int bid = blockIdx.x;
  int swz = (bid & 7) * 32 + (bid >> 3);
  const int brow = (swz >> 4) * 256;
  const int bcol = (swz & 15) * 256;

  // staging: thread t -> row t/4 (+128 for 2nd instr), 16B chunk t&3, XOR-swizzled source
  const int srow = tid >> 2;
  const int scsw = (tid & 3) ^ ((srow >> 1) & 3);
  const u16* Ag = A + (size_t)(brow + srow) * Kdim + scsw * 8;
  const u16* Bg = B + (size_t)(bcol + srow) * Kdim + scsw * 8;

  // ds_read: lane -> row r16, k-chunk kq, swizzled chunk ck
  const int r16 = lane & 15, kq = lane >> 4;
  const int ck  = kq ^ ((r16 >> 1) & 3);
  const int aoff = (wr * 128 + r16) * 32 + ck * 8;  // + m*512 per frag
  const int boff = (wc * 64 + r16) * 32 + ck * 8;   // + n*512 per frag

  f32x4 acc[8][4] = {};

  // prologue: stage subtiles 0,1,2 (12 loads); certify subtile 0 cross-wave
#pragma unroll
  for (int s = 0; s < 3; ++s) {
    stage_sub(Ag + s * 32, &Alds[s][0] + tid * 8);
    stage_sub(Bg + s * 32, &Blds[s][0] + tid * 8);
  }
  asm volatile("s_waitcnt vmcnt(8)" ::: "memory");
  __builtin_amdgcn_s_barrier();

  for (int s = 0; s < NSUB; ++s) {
    const int sl = s & 3;
    const u16* abase = &Alds[sl][0] + aoff;
    const u16* bbase = &Blds[sl][0] + boff;
    short8 a03[4], a47[4], bfr[4];

    // ---- issue all 12 ds_reads; pin first-8 group boundary ----
#pragma unroll
    for (int n = 0; n < 4; ++n) bfr[n] = *(const short8*)(bbase + n * 512);
#pragma unroll
    for (int m = 0; m < 4; ++m) a03[m] = *(const short8*)(abase + m * 512);
    __builtin_amdgcn_sched_barrier(0);   // bfr+a03 (8 reads) strictly before a47
#pragma unroll
    for (int m = 0; m < 4; ++m) a47[m] = *(const short8*)(abase + (m + 4) * 512);

    // ---- stage next subtile (A then B), then counted vmcnt certifying s+1 ----
    if (s + 3 < NSUB) {
      stage_sub(Ag + (s + 3) * 32, &Alds[(s + 3) & 3][0] + tid * 8);
      stage_sub(Bg + (s + 3) * 32, &Blds[(s + 3) & 3][0] + tid * 8);
    }
    if (s <= NSUB - 4)      asm volatile("s_waitcnt vmcnt(8)" ::: "memory");
    else if (s == NSUB - 3) asm volatile("s_waitcnt vmcnt(4)" ::: "memory");
    else if (s == NSUB - 2) asm volatile("s_waitcnt vmcnt(0)" ::: "memory");

    // ---- upper cluster: needs bfr+a03 only (first 8 reads, in-order DS) ----
    asm volatile("s_waitcnt lgkmcnt(4)" ::: "memory");
    __builtin_amdgcn_sched_barrier(0);
    __builtin_amdgcn_s_setprio(1);
#pragma unroll
    for (int m = 0; m < 4; ++m)
#pragma unroll
      for (int n = 0; n < 4; ++n)
        acc[m][n] = __builtin_amdgcn_mfma_f32_16x16x32_bf16(a03[m], bfr[n], acc[m][n], 0, 0, 0);
    __builtin_amdgcn_s_setprio(0);

    // ---- lower cluster: a47 drained (overlapped with upper MFMA) ----
    asm volatile("s_waitcnt lgkmcnt(0)" ::: "memory");
    __builtin_amdgcn_sched_barrier(0);
    __builtin_amdgcn_s_setprio(1);
#pragma unroll
    for (int m = 0; m < 4; ++m)
#pragma unroll
      for (int n = 0; n < 4; ++n)
        acc[m + 4][n] = __builtin_amdgcn_mfma_f32_16x16x32_bf16(a47[m], bfr[n], acc[m + 4][n], 0, 0, 0);
    __builtin_amdgcn_s_setprio(0);
    __builtin_amdgcn_s_barrier();   // single barrier per subtile
  }

  // epilogue: bias + per-feature LeakyReLU
  const int crow0 = brow + wr * 128 + (lane >> 4) * 4;
  const int ccol0 = bcol + wc * 64 + r16;
#pragma unroll
  for (int n = 0; n < 4; ++n) {
    int col = ccol0 + n * 16;
    float bv = bias[col], sv = slope[col];
#pragma unroll
    for (int m = 0; m < 8; ++m) {
      int row0 = crow0 + m * 16;
#pragma unroll
      for (int r = 0; r < 4; ++r) {
        float vv = acc[m][n][r] + bv;
        vv = vv < 0.f ? vv * sv : vv;
        if constexpr (OUTF32) {
          ((float*)Cv)[(size_t)(row0 + r) * NNODES + col] = vv;
        } else {
          ((u16*)Cv)[(size_t)(row0 + r) * NNODES + col] = bf16_rn(vv);
        }
      }
    }
  }
}

extern "C" void kernel_launch(void* const* d_in, const int* in_sizes, int n_in,
                              void* d_out, int out_size, void* d_ws, size_t ws_size,
                              hipStream_t stream) {
  const float* x     = (const float*)d_in[0];
  const float* ln_g  = (const float*)d_in[1];
  const float* ln_b  = (const float*)d_in[2];
  const float* W     = (const float*)d_in[3];
  const float* b     = (const float*)d_in[4];
  const float* slope = (const float*)d_in[5];
  float* out = (float*)d_out;

  char* ws = (char*)d_ws;
  u16* Wbuf  = (u16*)ws;                                   // 32 MB
  u16* lnbuf = (u16*)(ws + (size_t)32 * 1024 * 1024);      // 32 MB
  u16* ybuf  = (u16*)(ws + (size_t)64 * 1024 * 1024);      // 32 MB (bf16 y)

  const size_t WN = (size_t)NNODES * NNODES;
  const dim3 pgrid(16384 + NBATCH);

  for (int i = 0; i < NBLK; ++i) {
    if (i == 0)
      prep_kernel<true><<<pgrid, dim3(256), 0, stream>>>(W, Wbuf, (const void*)x,
                                                         ln_g, ln_b, lnbuf);
    else
      prep_kernel<false><<<pgrid, dim3(256), 0, stream>>>(W + WN * i, Wbuf, (const void*)ybuf,
                                                          ln_g + (size_t)i * NNODES,
                                                          ln_b + (size_t)i * NNODES, lnbuf);
    if (i == NBLK - 1)
      gemm256_kernel<true><<<dim3(256), dim3(512), 0, stream>>>(lnbuf, Wbuf,
                                                                b + (size_t)i * NNODES,
                                                                slope + (size_t)i * NNODES, (void*)out);
    else
      gemm256_kernel<false><<<dim3(256), dim3(512), 0, stream>>>(lnbuf, Wbuf,
                                                                 b + (size_t)i * NNODES,
                                                                 slope + (size_t)i * NNODES, (void*)ybuf);
  }
}

// Round 7
// 1119.165 us; speedup vs baseline: 1.3051x; 1.0563x over previous
//
#include <hip/hip_runtime.h>
#include <hip/hip_bf16.h>

#define NNODES 4096
#define NBATCH 4096
#define NBLK 8
#define LN_EPS 1e-5f

typedef __attribute__((ext_vector_type(8))) short short8;
typedef __attribute__((ext_vector_type(4))) float f32x4;
typedef __attribute__((ext_vector_type(4))) unsigned short u16x4;
typedef unsigned short u16;

__device__ __forceinline__ u16 bf16_rn(float f) {
  unsigned int u = __builtin_bit_cast(unsigned int, f);
  u += 0x7fffu + ((u >> 16) & 1u);
  return (u16)(u >> 16);
}

__device__ __forceinline__ float bf16_to_f(u16 h) {
  unsigned int u = ((unsigned int)h) << 16;
  return __builtin_bit_cast(float, u);
}

__device__ __forceinline__ void load_lds16(const void* g, void* l) {
  __builtin_amdgcn_global_load_lds((const __attribute__((address_space(1))) void*)g,
                                   (__attribute__((address_space(3))) void*)l,
                                   16, 0, 0);
}

// ---- merged prep: blocks [0,16384) convert W f32->bf16; [16384,16384+4096) LayerNorm ----
template <bool LNF32>
__global__ __launch_bounds__(256) void prep_kernel(const float* __restrict__ W,
                                                   u16* __restrict__ Wb,
                                                   const void* __restrict__ xin,
                                                   const float* __restrict__ g,
                                                   const float* __restrict__ bt,
                                                   u16* __restrict__ lnout) {
  __shared__ float sh[8];
  int t = threadIdx.x;
  if (blockIdx.x < 16384) {
    int idx = blockIdx.x * 256 + t;
    float4 v = ((const float4*)W)[idx];
    u16x4 o;
    o[0] = bf16_rn(v.x); o[1] = bf16_rn(v.y); o[2] = bf16_rn(v.z); o[3] = bf16_rn(v.w);
    ((u16x4*)Wb)[idx] = o;
    return;
  }
  int row = blockIdx.x - 16384;
  float f[16];
  float s = 0.f, ss = 0.f;
  if constexpr (LNF32) {
    const float4* xr = (const float4*)((const float*)xin + (size_t)row * NNODES);
#pragma unroll
    for (int q = 0; q < 4; ++q) {
      float4 v = xr[q * 256 + t];
      f[q * 4 + 0] = v.x; f[q * 4 + 1] = v.y; f[q * 4 + 2] = v.z; f[q * 4 + 3] = v.w;
      s  += v.x + v.y + v.z + v.w;
      ss += v.x * v.x + v.y * v.y + v.z * v.z + v.w * v.w;
    }
  } else {
    const u16* xr = (const u16*)xin + (size_t)row * NNODES;
#pragma unroll
    for (int q = 0; q < 2; ++q) {
      short8 v = *(const short8*)(xr + q * 2048 + t * 8);
#pragma unroll
      for (int j = 0; j < 8; ++j) {
        float fv = bf16_to_f((u16)v[j]);
        f[q * 8 + j] = fv;
        s += fv; ss += fv * fv;
      }
    }
  }
#pragma unroll
  for (int off = 32; off >= 1; off >>= 1) {
    s  += __shfl_xor(s, off, 64);
    ss += __shfl_xor(ss, off, 64);
  }
  int wid = t >> 6, lane = t & 63;
  if (lane == 0) { sh[wid] = s; sh[wid + 4] = ss; }
  __syncthreads();
  s  = sh[0] + sh[1] + sh[2] + sh[3];
  ss = sh[4] + sh[5] + sh[6] + sh[7];
  float mu  = s * (1.f / NNODES);
  float var = ss * (1.f / NNODES) - mu * mu;
  float rs  = rsqrtf(var + LN_EPS);
  if constexpr (LNF32) {
    u16x4* o = (u16x4*)(lnout + (size_t)row * NNODES);
    const float4* gv = (const float4*)g;
    const float4* bv = (const float4*)bt;
#pragma unroll
    for (int q = 0; q < 4; ++q) {
      int i = q * 256 + t;
      float4 gg = gv[i], bb = bv[i];
      u16x4 ov;
      ov[0] = bf16_rn((f[q * 4 + 0] - mu) * rs * gg.x + bb.x);
      ov[1] = bf16_rn((f[q * 4 + 1] - mu) * rs * gg.y + bb.y);
      ov[2] = bf16_rn((f[q * 4 + 2] - mu) * rs * gg.z + bb.z);
      ov[3] = bf16_rn((f[q * 4 + 3] - mu) * rs * gg.w + bb.w);
      o[i] = ov;
    }
  } else {
#pragma unroll
    for (int q = 0; q < 2; ++q) {
      int base = q * 2048 + t * 8;
      float4 g0 = ((const float4*)g)[base / 4], g1 = ((const float4*)g)[base / 4 + 1];
      float4 b0 = ((const float4*)bt)[base / 4], b1 = ((const float4*)bt)[base / 4 + 1];
      short8 sv;
      sv[0] = (short)bf16_rn((f[q * 8 + 0] - mu) * rs * g0.x + b0.x);
      sv[1] = (short)bf16_rn((f[q * 8 + 1] - mu) * rs * g0.y + b0.y);
      sv[2] = (short)bf16_rn((f[q * 8 + 2] - mu) * rs * g0.z + b0.z);
      sv[3] = (short)bf16_rn((f[q * 8 + 3] - mu) * rs * g0.w + b0.w);
      sv[4] = (short)bf16_rn((f[q * 8 + 4] - mu) * rs * g1.x + b1.x);
      sv[5] = (short)bf16_rn((f[q * 8 + 5] - mu) * rs * g1.y + b1.y);
      sv[6] = (short)bf16_rn((f[q * 8 + 6] - mu) * rs * g1.z + b1.z);
      sv[7] = (short)bf16_rn((f[q * 8 + 7] - mu) * rs * g1.w + b1.w);
      *(short8*)(lnout + (size_t)row * NNODES + base) = sv;
    }
  }
}

// ---- 256x256 bf16 NT GEMM, 8 waves, BK=64, 2-dbuf LDS, 8-phase schedule ----
// Phase: {ds_read frags | stage 1 half-tile (2 gload_lds) | [vmcnt] } barrier
//        lgkmcnt(0); setprio(1); 16 MFMA (one quadrant x K=64); setprio(0); barrier.
// Stage map: p0:A-lo(T+1) p1:A-hi(T+1) p2:B-lo(T+2) p3:B-hi(T+2)+vmcnt(4)
//            p4:A-lo(T+2) p5:A-hi(T+2) p6:B-lo(T+3) p7:B-hi(T+3)+vmcnt(4)
// vmcnt(4) leaves the 2 newest half-tiles outstanding => certifies tile T+1/T+2
// cross-wave via the following barrier. Buffer legality: each overwrite-issue is
// >=1 barrier after the buffer's last reads (A-buf freed after p2/p6 barrier,
// B-buf freed after p1/p5 barrier).

#define VMC(N) asm volatile("s_waitcnt vmcnt(" #N ")" ::: "memory")

#define STAGE_A(T, H)                                                          \
  { load_lds16(Asrc0 + (size_t)((H) * 128) * Kdim + (T) * 64,                  \
               ldsA + ((T) & 1) * 16384 + (H) * 8192 + tid * 8);               \
    load_lds16(Asrc0 + (size_t)((H) * 128 + 64) * Kdim + (T) * 64,             \
               ldsA + ((T) & 1) * 16384 + (H) * 8192 + 4096 + tid * 8); }

#define STAGE_B(T, H)                                                          \
  { load_lds16(Bsrc0 + (size_t)((H) * 128) * Kdim + (T) * 64,                  \
               ldsB + ((T) & 1) * 16384 + (H) * 8192 + tid * 8);               \
    load_lds16(Bsrc0 + (size_t)((H) * 128 + 64) * Kdim + (T) * 64,             \
               ldsB + ((T) & 1) * 16384 + (H) * 8192 + 4096 + tid * 8); }

#define PH(KT, MH, NH, STAGE_STMT, VM_STMT)                                    \
  {                                                                            \
    const u16* Ab = ldsA + ((KT) & 1) * 16384 + aBase + (MH) * 4096;           \
    const u16* Bb = ldsB + ((KT) & 1) * 16384 + bBase + (NH) * 2048;           \
    if ((NH) == 0) {                                                           \
      _Pragma("unroll") for (int mi = 0; mi < 4; ++mi) {                       \
        afr[mi][0] = *(const short8*)(Ab + mi * 1024 + gk0);                   \
        afr[mi][1] = *(const short8*)(Ab + mi * 1024 + gk1);                   \
      }                                                                        \
    }                                                                          \
    if ((MH) == 0) {                                                           \
      _Pragma("unroll") for (int ni = 0; ni < 2; ++ni) {                       \
        bfr[NH][ni][0] = *(const short8*)(Bb + ni * 1024 + gk0);               \
        bfr[NH][ni][1] = *(const short8*)(Bb + ni * 1024 + gk1);               \
      }                                                                        \
    }                                                                          \
    STAGE_STMT;                                                                \
    if ((NH) == 0 && (MH) == 0)                                                \
      asm volatile("s_waitcnt lgkmcnt(8)" ::: "memory");                       \
    VM_STMT;                                                                   \
    __builtin_amdgcn_s_barrier();                                              \
    asm volatile("s_waitcnt lgkmcnt(0)" ::: "memory");                         \
    __builtin_amdgcn_sched_barrier(0);                                         \
    __builtin_amdgcn_s_setprio(1);                                             \
    _Pragma("unroll") for (int mi = 0; mi < 4; ++mi)                           \
      _Pragma("unroll") for (int ni = 0; ni < 2; ++ni) {                       \
        acc[(MH) * 4 + mi][(NH) * 2 + ni] =                                    \
          __builtin_amdgcn_mfma_f32_16x16x32_bf16(afr[mi][0], bfr[NH][ni][0],  \
            acc[(MH) * 4 + mi][(NH) * 2 + ni], 0, 0, 0);                       \
        acc[(MH) * 4 + mi][(NH) * 2 + ni] =                                    \
          __builtin_amdgcn_mfma_f32_16x16x32_bf16(afr[mi][1], bfr[NH][ni][1],  \
            acc[(MH) * 4 + mi][(NH) * 2 + ni], 0, 0, 0);                       \
      }                                                                        \
    __builtin_amdgcn_s_setprio(0);                                             \
    __builtin_amdgcn_s_barrier();                                              \
  }

template <bool OUTF32>
__global__ __launch_bounds__(512, 2) void gemm256_kernel(const u16* __restrict__ A,
                                                         const u16* __restrict__ B,
                                                         const float* __restrict__ bias,
                                                         const float* __restrict__ slope,
                                                         void* __restrict__ Cv) {
  constexpr int Kdim = NNODES;
  __shared__ u16 lds[65536];           // 128KB: A in [0,32768), B in [32768,65536)
  u16* ldsA = lds;
  u16* ldsB = lds + 32768;

  const int tid  = threadIdx.x;
  const int lane = tid & 63;
  const int wid  = tid >> 6;
  const int wr   = wid >> 2;           // 0..1 : 128-row half
  const int wc   = wid & 3;            // 0..3 : 64-col quarter

  // XCD-aware bijective swizzle (256 blocks, 8 XCDs)
  int bid = blockIdx.x;
  int swz = (bid & 7) * 32 + (bid >> 3);
  const int brow = (swz >> 4) * 256;
  const int bcol = (swz & 15) * 256;

  // staging source: thread t -> row t/8, granule (t&7) XOR (row&7)  (pre-swizzled)
  const int srow = tid >> 3;
  const int sg   = ((tid & 7) ^ (srow & 7)) * 8;
  const u16* Asrc0 = A + (size_t)(brow + srow) * Kdim + sg;
  const u16* Bsrc0 = B + (size_t)(bcol + srow) * Kdim + sg;

  // ds_read: lane -> row r16, k-quarter kq; granule g = (ks*4+kq) ^ (r16&7)
  const int r16 = lane & 15, kq = lane >> 4;
  const int g0  = kq ^ (r16 & 7);
  const int gk0 = g0 * 8, gk1 = (g0 ^ 4) * 8;
  const int aBase = wr * 8192 + r16 * 64;
  const int bBase = (wc >> 1) * 8192 + ((wc & 1) * 64 + r16) * 64;

  f32x4 acc[8][4] = {};
  short8 afr[4][2], bfr[2][2][2];

  // prologue: stage B(0), A(0), B(1) halves (12 loads, steady-state order);
  // vmcnt(4) certifies tile 0 (leaves B-lo(1),B-hi(1) outstanding)
  STAGE_B(0, 0) STAGE_B(0, 1) STAGE_A(0, 0) STAGE_A(0, 1) STAGE_B(1, 0) STAGE_B(1, 1)
  VMC(4);
  __builtin_amdgcn_s_barrier();

  for (int t = 0; t < 31; ++t) {
    const int T = 2 * t;
    PH(T,     0, 0, STAGE_A(T + 1, 0), ;)
    PH(T,     0, 1, STAGE_A(T + 1, 1), ;)
    PH(T,     1, 0, STAGE_B(T + 2, 0), ;)
    PH(T,     1, 1, STAGE_B(T + 2, 1), VMC(4))
    PH(T + 1, 0, 0, STAGE_A(T + 2, 0), ;)
    PH(T + 1, 0, 1, STAGE_A(T + 2, 1), ;)
    PH(T + 1, 1, 0, STAGE_B(T + 3, 0), ;)
    PH(T + 1, 1, 1, STAGE_B(T + 3, 1), VMC(4))
  }
  // tail: T = 62 (stage only A(63); vmcnt(0) certifies tile 63)
  PH(62, 0, 0, STAGE_A(63, 0), ;)
  PH(62, 0, 1, STAGE_A(63, 1), ;)
  PH(62, 1, 0, ;, ;)
  PH(62, 1, 1, ;, VMC(0))
  PH(63, 0, 0, ;, ;)
  PH(63, 0, 1, ;, ;)
  PH(63, 1, 0, ;, ;)
  PH(63, 1, 1, ;, ;)

  // epilogue: bias + per-feature LeakyReLU
  const int crow0 = brow + wr * 128 + (lane >> 4) * 4;
  const int ccol0 = bcol + wc * 64 + r16;
#pragma unroll
  for (int n = 0; n < 4; ++n) {
    int col = ccol0 + n * 16;
    float bv = bias[col], sv = slope[col];
#pragma unroll
    for (int m = 0; m < 8; ++m) {
      int row0 = crow0 + m * 16;
#pragma unroll
      for (int r = 0; r < 4; ++r) {
        float vv = acc[m][n][r] + bv;
        vv = vv < 0.f ? vv * sv : vv;
        if constexpr (OUTF32) {
          ((float*)Cv)[(size_t)(row0 + r) * NNODES + col] = vv;
        } else {
          ((u16*)Cv)[(size_t)(row0 + r) * NNODES + col] = bf16_rn(vv);
        }
      }
    }
  }
}

extern "C" void kernel_launch(void* const* d_in, const int* in_sizes, int n_in,
                              void* d_out, int out_size, void* d_ws, size_t ws_size,
                              hipStream_t stream) {
  const float* x     = (const float*)d_in[0];
  const float* ln_g  = (const float*)d_in[1];
  const float* ln_b  = (const float*)d_in[2];
  const float* W     = (const float*)d_in[3];
  const float* b     = (const float*)d_in[4];
  const float* slope = (const float*)d_in[5];
  float* out = (float*)d_out;

  char* ws = (char*)d_ws;
  u16* Wbuf  = (u16*)ws;                                   // 32 MB
  u16* lnbuf = (u16*)(ws + (size_t)32 * 1024 * 1024);      // 32 MB
  u16* ybuf  = (u16*)(ws + (size_t)64 * 1024 * 1024);      // 32 MB (bf16 y)

  const size_t WN = (size_t)NNODES * NNODES;
  const dim3 pgrid(16384 + NBATCH);

  for (int i = 0; i < NBLK; ++i) {
    if (i == 0)
      prep_kernel<true><<<pgrid, dim3(256), 0, stream>>>(W, Wbuf, (const void*)x,
                                                         ln_g, ln_b, lnbuf);
    else
      prep_kernel<false><<<pgrid, dim3(256), 0, stream>>>(W + WN * i, Wbuf, (const void*)ybuf,
                                                          ln_g + (size_t)i * NNODES,
                                                          ln_b + (size_t)i * NNODES, lnbuf);
    if (i == NBLK - 1)
      gemm256_kernel<true><<<dim3(256), dim3(512), 0, stream>>>(lnbuf, Wbuf,
                                                                b + (size_t)i * NNODES,
                                                                slope + (size_t)i * NNODES, (void*)out);
    else
      gemm256_kernel<false><<<dim3(256), dim3(512), 0, stream>>>(lnbuf, Wbuf,
                                                                 b + (size_t)i * NNODES,
                                                                 slope + (size_t)i * NNODES, (void*)ybuf);
  }
}